// Round 5
// baseline (495.247 us; speedup 1.0000x reference)
//
#include <hip/hip_runtime.h>

#define D_IN 128
#define BSH 7              // nodes per bucket = 128 = 1<<BSH

typedef unsigned short u16;
typedef __attribute__((ext_vector_type(8))) short short8;
typedef __attribute__((ext_vector_type(4))) float f32x4;

static inline size_t align_up(size_t v, size_t a) { return (v + a - 1) & ~(a - 1); }

__device__ inline u16 f2bf(float f) {
    union { float f; unsigned int u; } c; c.f = f;
    unsigned int u = c.u;
    return (u16)((u + 0x7fffu + ((u >> 16) & 1u)) >> 16);   // RNE
}
__device__ inline float bflo(unsigned int u) {
    union { unsigned int u; float f; } c; c.u = u << 16; return c.f;
}
__device__ inline float bfhi(unsigned int u) {
    union { unsigned int u; float f; } c; c.u = u & 0xffff0000u; return c.f;
}
__device__ inline unsigned int packbf2(float lo, float hi) {
    return (unsigned int)f2bf(lo) | ((unsigned int)f2bf(hi) << 16);
}

#define GLDS16(gp, lp) \
    __builtin_amdgcn_global_load_lds((const __attribute__((address_space(1))) void*)(gp), \
                                     (__attribute__((address_space(3))) void*)(lp), 16, 0, 0)

// ---------------- prep: cast x->bf16 + pack weights + zero bucket hist ----------------
__global__ void k_prep(const float* __restrict__ x, u16* __restrict__ xb, int total4,
                       int* __restrict__ bhist, int NB,
                       const float* __restrict__ Ws1, const float* __restrict__ Wn1,
                       const float* __restrict__ Ws2, const float* __restrict__ Wn2,
                       u16* __restrict__ W1t, u16* __restrict__ W2t) {
    int i = blockIdx.x * blockDim.x + threadIdx.x;
    if (i < total4) {
        float4 v = ((const float4*)x)[i];
        uint2 o;
        o.x = packbf2(v.x, v.y);
        o.y = packbf2(v.z, v.w);
        *(uint2*)&xb[(size_t)i * 4] = o;
    }
    if (i < NB) bhist[i] = 0;
    if (i < 128 * 256) {
        int nn = i >> 8, kk = i & 255;
        float v = (kk < 128) ? Ws1[kk * 128 + nn] : Wn1[(kk - 128) * 128 + nn];
        W1t[i] = f2bf(v);
    }
    if (i < 128 * 128) {
        int nn = i >> 7, kk = i & 127;
        float v = (nn < 64) ? Ws2[kk * 64 + nn] : Wn2[kk * 64 + (nn - 64)];
        W2t[i] = f2bf(v);
    }
}

// ---------------- bucket histogram, LDS-privatized ----------------
__global__ void k_binhist(const int* __restrict__ dst, int* __restrict__ bhist, int e, int NB) {
    __shared__ int h[1024];
    int t = threadIdx.x;
    for (int j = t; j < 1024; j += 256) h[j] = 0;
    __syncthreads();
    for (int i = blockIdx.x * 256 + t; i < e; i += gridDim.x * 256)
        atomicAdd(&h[dst[i] >> BSH], 1);
    __syncthreads();
    for (int j = t; j < NB; j += 256)
        if (h[j]) atomicAdd(&bhist[j], h[j]);
}

// ---------------- exclusive scan of bucket sums (single block; NB <= 1024) ----------------
__global__ void k_binscan(const int* __restrict__ bhist, int* __restrict__ boff,
                          int* __restrict__ bcur, int NB) {
    __shared__ int sd[256];
    int t = threadIdx.x;
    int base = t * 4;
    int v[4]; int s = 0;
    #pragma unroll
    for (int j = 0; j < 4; ++j) { v[j] = (base + j < NB) ? bhist[base + j] : 0; s += v[j]; }
    sd[t] = s;
    __syncthreads();
    #pragma unroll
    for (int off = 1; off < 256; off <<= 1) {
        int x = (t >= off) ? sd[t - off] : 0;
        __syncthreads();
        sd[t] += x;
        __syncthreads();
    }
    int run = sd[t] - s;
    #pragma unroll
    for (int j = 0; j < 4; ++j) {
        if (base + j < NB) { boff[base + j] = run; bcur[base + j] = run; }
        run += v[j];
    }
    if (t == 255) boff[NB] = run;   // total = e
}

// ---------------- bin edges: pairs[pos] = (src<<BSH) | (dst & 127) ----------------
__global__ void k_binscatter(const int* __restrict__ src, const int* __restrict__ dst,
                             int* __restrict__ bcur, unsigned int* __restrict__ pairs, int e) {
    int i = blockIdx.x * blockDim.x + threadIdx.x;
    if (i >= e) return;
    int d = dst[i];
    int b = d >> BSH;
    int pos = atomicAdd(&bcur[b], 1);
    pairs[pos] = ((unsigned int)src[i] << BSH) | (unsigned int)(d & 127);
}

// ---------------- per-bucket: LDS degree+scan, write rs[], place CSR segment ----------------
__global__ void k_bucket(const unsigned int* __restrict__ pairs, const int* __restrict__ boff,
                         int* __restrict__ rs, int* __restrict__ csr, int n, int e) {
    __shared__ int sdeg[128];
    __shared__ int stmp[128];
    __shared__ int scur[128];
    int b = blockIdx.x;
    int t = threadIdx.x;
    int node0 = b << BSH;
    int bstart = boff[b];
    int bend = boff[b + 1];
    if (t < 128) sdeg[t] = 0;
    __syncthreads();
    for (int i = bstart + t; i < bend; i += 256)
        atomicAdd(&sdeg[pairs[i] & 127], 1);
    __syncthreads();
    if (t < 128) stmp[t] = sdeg[t];
    __syncthreads();
    #pragma unroll
    for (int off = 1; off < 128; off <<= 1) {
        int v = (t < 128 && t >= off) ? stmp[t - off] : 0;
        __syncthreads();
        if (t < 128) stmp[t] += v;
        __syncthreads();
    }
    if (t < 128) {
        int excl = stmp[t] - sdeg[t];
        scur[t] = excl;
        int node = node0 + t;
        if (node < n) rs[node] = bstart + excl;
    }
    if (b == (int)gridDim.x - 1 && t == 0) rs[n] = e;
    __syncthreads();
    for (int i = bstart + t; i < bend; i += 256) {
        unsigned int u = pairs[i];
        int l = (int)(u & 127);
        int p = atomicAdd(&scur[l], 1);
        csr[bstart + p] = (int)(u >> BSH);
    }
}

// ---------------- layer-1 gather-aggregate (bf16 rows, fp32 accum, bf16 out) ----------------
// one wave per node; 16 lanes x 16B cover 128-bf16 row; 4 quads, 2-deep pipelined
__global__ void k_agg1(const u16* __restrict__ xb, const int* __restrict__ rs,
                       const int* __restrict__ csr, u16* __restrict__ hnb, int n) {
    int wid = (blockIdx.x * blockDim.x + threadIdx.x) >> 6;
    int lane = threadIdx.x & 63;
    if (wid >= n) return;
    int chunk = lane & 15;
    int quad = lane >> 4;
    int start = rs[wid];
    int deg = rs[wid + 1] - start;
    float inv = 1.0f / (1.0f + (float)deg);
    const int* nb = csr + start;
    float acc[8] = {};
    int k = quad;
    for (; k + 4 < deg; k += 8) {
        int s0 = nb[k], s1 = nb[k + 4];
        uint4 u0 = *(const uint4*)(xb + (size_t)s0 * 128 + chunk * 8);
        uint4 u1 = *(const uint4*)(xb + (size_t)s1 * 128 + chunk * 8);
        acc[0] += bflo(u0.x); acc[1] += bfhi(u0.x);
        acc[2] += bflo(u0.y); acc[3] += bfhi(u0.y);
        acc[4] += bflo(u0.z); acc[5] += bfhi(u0.z);
        acc[6] += bflo(u0.w); acc[7] += bfhi(u0.w);
        acc[0] += bflo(u1.x); acc[1] += bfhi(u1.x);
        acc[2] += bflo(u1.y); acc[3] += bfhi(u1.y);
        acc[4] += bflo(u1.z); acc[5] += bfhi(u1.z);
        acc[6] += bflo(u1.w); acc[7] += bfhi(u1.w);
    }
    if (k < deg) {
        int s = nb[k];
        uint4 u = *(const uint4*)(xb + (size_t)s * 128 + chunk * 8);
        acc[0] += bflo(u.x); acc[1] += bfhi(u.x);
        acc[2] += bflo(u.y); acc[3] += bfhi(u.y);
        acc[4] += bflo(u.z); acc[5] += bfhi(u.z);
        acc[6] += bflo(u.w); acc[7] += bfhi(u.w);
    }
    #pragma unroll
    for (int t = 0; t < 8; ++t) {
        acc[t] += __shfl_xor(acc[t], 16);
        acc[t] += __shfl_xor(acc[t], 32);
    }
    if (quad == 0) {
        uint4 u = *(const uint4*)(xb + (size_t)wid * 128 + chunk * 8);  // self
        acc[0] += bflo(u.x); acc[1] += bfhi(u.x);
        acc[2] += bflo(u.y); acc[3] += bfhi(u.y);
        acc[4] += bflo(u.z); acc[5] += bfhi(u.z);
        acc[6] += bflo(u.w); acc[7] += bfhi(u.w);
        uint4 o;
        o.x = packbf2(acc[0] * inv, acc[1] * inv);
        o.y = packbf2(acc[2] * inv, acc[3] * inv);
        o.z = packbf2(acc[4] * inv, acc[5] * inv);
        o.w = packbf2(acc[6] * inv, acc[7] * inv);
        *(uint4*)(hnb + (size_t)wid * 128 + chunk * 8) = o;
    }
}

// ---------------- MFMA GEMM1: h1b = relu([xb|hnb] @ W1cat + b1), bf16 out ----------------
__launch_bounds__(256)
__global__ void k_gemm1_mfma(const u16* __restrict__ xb, const u16* hnb,
                             const u16* __restrict__ W1t, const float* __restrict__ b1,
                             u16* h1b, int n) {
    __shared__ u16 As[128 * 32];
    __shared__ u16 Bs[128 * 32];
    int tid = threadIdx.x;
    int lane = tid & 63;
    int wave = tid >> 6;
    int wr = wave >> 1, wc = wave & 1;
    int row0 = blockIdx.x * 128;
    int srow = tid >> 2;
    int scol = (tid & 3) * 8;
    int m = lane & 15;
    int q = lane >> 4;

    f32x4 zero = {0.f, 0.f, 0.f, 0.f};
    f32x4 acc[4][4];
    #pragma unroll
    for (int i = 0; i < 4; ++i)
        #pragma unroll
        for (int j = 0; j < 4; ++j) acc[i][j] = zero;

    for (int kb = 0; kb < 8; ++kb) {
        const u16* Asrc = (kb < 4) ? xb : hnb;
        int kbase = (kb & 3) * 32;
        int krowB = kb * 32;
        #pragma unroll
        for (int t = 0; t < 2; ++t) {
            int gr = row0 + t * 64 + srow;
            if (gr >= n) gr = n - 1;
            GLDS16(Asrc + (size_t)gr * 128 + kbase + scol, As + t * 2048 + wave * 512);
        }
        #pragma unroll
        for (int t = 0; t < 2; ++t) {
            int nn = t * 64 + srow;
            GLDS16(W1t + (size_t)nn * 256 + krowB + scol, Bs + t * 2048 + wave * 512);
        }
        __syncthreads();
        #pragma unroll
        for (int i = 0; i < 4; ++i) {
            short8 a = *(const short8*)&As[(wr * 64 + i * 16 + m) * 32 + q * 8];
            #pragma unroll
            for (int j = 0; j < 4; ++j) {
                short8 b = *(const short8*)&Bs[(wc * 64 + j * 16 + m) * 32 + q * 8];
                acc[i][j] = __builtin_amdgcn_mfma_f32_16x16x32_bf16(a, b, acc[i][j], 0, 0, 0);
            }
        }
        __syncthreads();
    }
    #pragma unroll
    for (int i = 0; i < 4; ++i) {
        int grow = row0 + wr * 64 + i * 16 + q * 4;
        #pragma unroll
        for (int j = 0; j < 4; ++j) {
            int col = wc * 64 + j * 16 + m;
            float bias = b1[col];
            #pragma unroll
            for (int r = 0; r < 4; ++r) {
                int gr = grow + r;
                if (gr < n) h1b[(size_t)gr * 128 + col] = f2bf(fmaxf(acc[i][j][r] + bias, 0.f));
            }
        }
    }
}

// ---------------- MFMA GEMM2: qp = h1b @ [Ws2|Wn2] (cols 0..63=q, 64..127=p) ----------------
__launch_bounds__(256)
__global__ void k_gemm2_mfma(const u16* __restrict__ h1b, const u16* __restrict__ W2t,
                             u16* __restrict__ qp, int n) {
    __shared__ u16 As[128 * 32];
    __shared__ u16 Bs[128 * 32];
    int tid = threadIdx.x;
    int lane = tid & 63;
    int wave = tid >> 6;
    int wr = wave >> 1, wc = wave & 1;
    int row0 = blockIdx.x * 128;
    int srow = tid >> 2;
    int scol = (tid & 3) * 8;
    int m = lane & 15;
    int q = lane >> 4;

    f32x4 zero = {0.f, 0.f, 0.f, 0.f};
    f32x4 acc[4][4];
    #pragma unroll
    for (int i = 0; i < 4; ++i)
        #pragma unroll
        for (int j = 0; j < 4; ++j) acc[i][j] = zero;

    for (int kb = 0; kb < 4; ++kb) {
        int kbase = kb * 32;
        #pragma unroll
        for (int t = 0; t < 2; ++t) {
            int gr = row0 + t * 64 + srow;
            if (gr >= n) gr = n - 1;
            GLDS16(h1b + (size_t)gr * 128 + kbase + scol, As + t * 2048 + wave * 512);
        }
        #pragma unroll
        for (int t = 0; t < 2; ++t) {
            int nn = t * 64 + srow;
            GLDS16(W2t + (size_t)nn * 128 + kbase + scol, Bs + t * 2048 + wave * 512);
        }
        __syncthreads();
        #pragma unroll
        for (int i = 0; i < 4; ++i) {
            short8 a = *(const short8*)&As[(wr * 64 + i * 16 + m) * 32 + q * 8];
            #pragma unroll
            for (int j = 0; j < 4; ++j) {
                short8 b = *(const short8*)&Bs[(wc * 64 + j * 16 + m) * 32 + q * 8];
                acc[i][j] = __builtin_amdgcn_mfma_f32_16x16x32_bf16(a, b, acc[i][j], 0, 0, 0);
            }
        }
        __syncthreads();
    }
    #pragma unroll
    for (int i = 0; i < 4; ++i) {
        int grow = row0 + wr * 64 + i * 16 + q * 4;
        #pragma unroll
        for (int j = 0; j < 4; ++j) {
            int col = wc * 64 + j * 16 + m;
            #pragma unroll
            for (int r = 0; r < 4; ++r) {
                int gr = grow + r;
                if (gr < n) qp[(size_t)gr * 128 + col] = f2bf(acc[i][j][r]);
            }
        }
    }
}

// ---------------- layer-2 gather-aggregate + epilogue ----------------
__global__ void k_agg2(const u16* __restrict__ qp, const int* __restrict__ rs,
                       const int* __restrict__ csr, const float* __restrict__ b2,
                       float* __restrict__ out, int n) {
    int wid = (blockIdx.x * blockDim.x + threadIdx.x) >> 6;
    int lane = threadIdx.x & 63;
    if (wid >= n) return;
    int chunk = lane & 7;
    int oct = lane >> 3;
    int start = rs[wid];
    int deg = rs[wid + 1] - start;
    float inv = 1.0f / (1.0f + (float)deg);
    const int* nb = csr + start;
    float acc[8] = {};
    for (int k = oct; k < deg; k += 8) {
        int s = nb[k];
        uint4 u = *(const uint4*)(qp + (size_t)s * 128 + 64 + chunk * 8);
        acc[0] += bflo(u.x); acc[1] += bfhi(u.x);
        acc[2] += bflo(u.y); acc[3] += bfhi(u.y);
        acc[4] += bflo(u.z); acc[5] += bfhi(u.z);
        acc[6] += bflo(u.w); acc[7] += bfhi(u.w);
    }
    #pragma unroll
    for (int t = 0; t < 8; ++t) {
        acc[t] += __shfl_xor(acc[t], 8);
        acc[t] += __shfl_xor(acc[t], 16);
        acc[t] += __shfl_xor(acc[t], 32);
    }
    if (oct == 0) {
        uint4 up = *(const uint4*)(qp + (size_t)wid * 128 + 64 + chunk * 8); // self p
        uint4 uq = *(const uint4*)(qp + (size_t)wid * 128 + chunk * 8);      // q
        float o[8];
        o[0] = (acc[0] + bflo(up.x)) * inv + bflo(uq.x);
        o[1] = (acc[1] + bfhi(up.x)) * inv + bfhi(uq.x);
        o[2] = (acc[2] + bflo(up.y)) * inv + bflo(uq.y);
        o[3] = (acc[3] + bfhi(up.y)) * inv + bfhi(uq.y);
        o[4] = (acc[4] + bflo(up.z)) * inv + bflo(uq.z);
        o[5] = (acc[5] + bfhi(up.z)) * inv + bfhi(uq.z);
        o[6] = (acc[6] + bflo(up.w)) * inv + bflo(uq.w);
        o[7] = (acc[7] + bfhi(up.w)) * inv + bfhi(uq.w);
        float* op = out + (size_t)wid * 64 + chunk * 8;
        const float* bp = b2 + chunk * 8;
        *(float4*)(op + 0) = make_float4(o[0] + bp[0], o[1] + bp[1], o[2] + bp[2], o[3] + bp[3]);
        *(float4*)(op + 4) = make_float4(o[4] + bp[4], o[5] + bp[5], o[6] + bp[6], o[7] + bp[7]);
    }
}

extern "C" void kernel_launch(void* const* d_in, const int* in_sizes, int n_in,
                              void* d_out, int out_size, void* d_ws, size_t ws_size,
                              hipStream_t stream) {
    const float* x   = (const float*)d_in[0];
    const int*   src = (const int*)d_in[1];
    const int*   dst = (const int*)d_in[2];
    const float* Ws1 = (const float*)d_in[3];
    const float* Wn1 = (const float*)d_in[4];
    const float* b1  = (const float*)d_in[5];
    const float* Ws2 = (const float*)d_in[6];
    const float* Wn2 = (const float*)d_in[7];
    const float* b2  = (const float*)d_in[8];
    int n = in_sizes[0] / D_IN;
    int e = in_sizes[1];
    int NB = (n + 127) >> BSH;     // <= 1024 for n <= 131072

    char* ws = (char*)d_ws;
    size_t off = 0;
    int* bhist = (int*)(ws + off); off = align_up(off + (size_t)(NB + 1) * 4, 256);
    int* boff  = (int*)(ws + off); off = align_up(off + (size_t)(NB + 1) * 4, 256);
    int* bcur  = (int*)(ws + off); off = align_up(off + (size_t)(NB + 1) * 4, 256);
    unsigned int* pairs = (unsigned int*)(ws + off); off = align_up(off + (size_t)e * 4, 256);
    int* rs    = (int*)(ws + off); off = align_up(off + (size_t)(n + 1) * 4, 256);
    int* csr   = (int*)(ws + off); off = align_up(off + (size_t)e * 4, 256);
    u16* xb    = (u16*)(ws + off); off = align_up(off + (size_t)n * 128 * 2, 256);
    u16* hnb   = (u16*)(ws + off); off = align_up(off + (size_t)n * 128 * 2, 256);
    u16* qp    = (u16*)(ws + off); off = align_up(off + (size_t)n * 128 * 2, 256);
    u16* W1t   = (u16*)(ws + off); off = align_up(off + (size_t)128 * 256 * 2, 256);
    u16* W2t   = (u16*)(ws + off); off = align_up(off + (size_t)128 * 128 * 2, 256);
    u16* h1b = hnb;   // safe alias: gemm1 reads/writes only its own block rows
    float* outp = (float*)d_out;

    const int B = 256;
    k_prep<<<(n * 32 + B - 1) / B, B, 0, stream>>>(x, xb, n * 32, bhist, NB,
                                                   Ws1, Wn1, Ws2, Wn2, W1t, W2t);
    k_binhist<<<128, B, 0, stream>>>(dst, bhist, e, NB);
    k_binscan<<<1, 256, 0, stream>>>(bhist, boff, bcur, NB);
    k_binscatter<<<(e + B - 1) / B, B, 0, stream>>>(src, dst, bcur, pairs, e);
    k_bucket<<<NB, 256, 0, stream>>>(pairs, boff, rs, csr, n, e);
    k_agg1<<<(n + 3) / 4, B, 0, stream>>>(xb, rs, csr, hnb, n);
    k_gemm1_mfma<<<(n + 127) / 128, 256, 0, stream>>>(xb, hnb, W1t, b1, h1b, n);
    k_gemm2_mfma<<<(n + 127) / 128, 256, 0, stream>>>(h1b, W2t, qp, n);
    k_agg2<<<(n + 3) / 4, B, 0, stream>>>(qp, rs, csr, b2, outp, n);
}

// Round 6
// 280.354 us; speedup vs baseline: 1.7665x; 1.7665x over previous
//
#include <hip/hip_runtime.h>

#define D_IN 128
#define BSH 7              // nodes per bucket = 128
#define NW  128            // binning workgroups (phase A/C)

typedef unsigned short u16;
typedef __attribute__((ext_vector_type(8))) short short8;
typedef __attribute__((ext_vector_type(4))) float f32x4;

static inline size_t align_up(size_t v, size_t a) { return (v + a - 1) & ~(a - 1); }

__device__ inline u16 f2bf(float f) {
    union { float f; unsigned int u; } c; c.f = f;
    unsigned int u = c.u;
    return (u16)((u + 0x7fffu + ((u >> 16) & 1u)) >> 16);   // RNE
}
__device__ inline float bflo(unsigned int u) {
    union { unsigned int u; float f; } c; c.u = u << 16; return c.f;
}
__device__ inline float bfhi(unsigned int u) {
    union { unsigned int u; float f; } c; c.u = u & 0xffff0000u; return c.f;
}
__device__ inline unsigned int packbf2(float lo, float hi) {
    return (unsigned int)f2bf(lo) | ((unsigned int)f2bf(hi) << 16);
}

#define GLDS16(gp, lp) \
    __builtin_amdgcn_global_load_lds((const __attribute__((address_space(1))) void*)(gp), \
                                     (__attribute__((address_space(3))) void*)(lp), 16, 0, 0)

// ---------------- prep: cast x->bf16 + pack weights ----------------
__global__ void k_prep(const float* __restrict__ x, u16* __restrict__ xb, int total4,
                       const float* __restrict__ Ws1, const float* __restrict__ Wn1,
                       const float* __restrict__ Ws2, const float* __restrict__ Wn2,
                       u16* __restrict__ W1t, u16* __restrict__ W2t) {
    int i = blockIdx.x * blockDim.x + threadIdx.x;
    if (i < total4) {
        float4 v = ((const float4*)x)[i];
        uint2 o;
        o.x = packbf2(v.x, v.y);
        o.y = packbf2(v.z, v.w);
        *(uint2*)&xb[(size_t)i * 4] = o;
    }
    if (i < 128 * 256) {
        int nn = i >> 8, kk = i & 255;
        float v = (kk < 128) ? Ws1[kk * 128 + nn] : Wn1[(kk - 128) * 128 + nn];
        W1t[i] = f2bf(v);
    }
    if (i < 128 * 128) {
        int nn = i >> 7, kk = i & 127;
        float v = (nn < 64) ? Ws2[kk * 64 + nn] : Wn2[kk * 64 + (nn - 64)];
        W2t[i] = f2bf(v);
    }
}

// ---------------- phase A: per-WG bucket histogram -> table[bucket][wg] ----------------
__global__ void k_whist(const int* __restrict__ dst, int* __restrict__ table,
                        int e, int NB, int chunk) {
    __shared__ int h[1024];
    int w = blockIdx.x;
    int t = threadIdx.x;
    for (int j = t; j < 1024; j += 256) h[j] = 0;
    __syncthreads();
    int lo = w * chunk;
    int hi = lo + chunk; if (hi > e) hi = e;
    for (int i = lo + t; i < hi; i += 256)
        atomicAdd(&h[dst[i] >> BSH], 1);
    __syncthreads();
    for (int b = t; b < NB; b += 256)
        table[b * NW + w] = h[b];
}

// ---------------- scan 1: per-block (1024 elems) exclusive scan in place + block sums ----------------
__global__ void k_scan1(int* __restrict__ a, int* __restrict__ bsum, int T) {
    __shared__ int sd[256];
    int t = threadIdx.x;
    int base = blockIdx.x * 1024 + t * 4;
    int v[4]; int s = 0;
    #pragma unroll
    for (int j = 0; j < 4; ++j) { v[j] = (base + j < T) ? a[base + j] : 0; s += v[j]; }
    sd[t] = s;
    __syncthreads();
    #pragma unroll
    for (int off = 1; off < 256; off <<= 1) {
        int x = (t >= off) ? sd[t - off] : 0;
        __syncthreads();
        sd[t] += x;
        __syncthreads();
    }
    int run = sd[t] - s;
    #pragma unroll
    for (int j = 0; j < 4; ++j) {
        if (base + j < T) a[base + j] = run;
        run += v[j];
    }
    if (t == 255) bsum[blockIdx.x] = sd[255];
}

// ---------------- scan 2: single block, exclusive scan of block sums (nb <= 128) ----------------
__global__ void k_scan2(int* __restrict__ bsum, int nb) {
    __shared__ int sd[128];
    int t = threadIdx.x;
    int own = (t < nb) ? bsum[t] : 0;
    sd[t] = own;
    __syncthreads();
    #pragma unroll
    for (int off = 1; off < 128; off <<= 1) {
        int x = (t >= off) ? sd[t - off] : 0;
        __syncthreads();
        sd[t] += x;
        __syncthreads();
    }
    if (t < nb) bsum[t] = sd[t] - own;
}

// ---------------- scan 3: add block offsets ----------------
__global__ void k_scan3(int* __restrict__ a, const int* __restrict__ bsum, int T) {
    int i = blockIdx.x * blockDim.x + threadIdx.x;
    if (i < T) a[i] += bsum[i >> 10];
}

// ---------------- phase C: place pairs at private offsets (no global atomics) ----------------
__global__ void k_wplace(const int* __restrict__ src, const int* __restrict__ dst,
                         const int* __restrict__ table, unsigned int* __restrict__ pairs,
                         int e, int NB, int chunk) {
    __shared__ int cur[1024];
    int w = blockIdx.x;
    int t = threadIdx.x;
    for (int b = t; b < NB; b += 256) cur[b] = table[b * NW + w];
    __syncthreads();
    int lo = w * chunk;
    int hi = lo + chunk; if (hi > e) hi = e;
    for (int i = lo + t; i < hi; i += 256) {
        int d = dst[i];
        int p = atomicAdd(&cur[d >> BSH], 1);
        pairs[p] = ((unsigned int)src[i] << BSH) | (unsigned int)(d & 127);
    }
}

// ---------------- per-bucket: LDS degree+scan, write rs[], place CSR segment ----------------
__global__ void k_bucket(const unsigned int* __restrict__ pairs, const int* __restrict__ table,
                         int* __restrict__ rs, int* __restrict__ csr, int n, int e, int NB) {
    __shared__ int sdeg[128];
    __shared__ int stmp[128];
    __shared__ int scur[128];
    int b = blockIdx.x;
    int t = threadIdx.x;
    int node0 = b << BSH;
    int bstart = table[b * NW];
    int bend = (b + 1 < NB) ? table[(b + 1) * NW] : e;
    if (t < 128) sdeg[t] = 0;
    __syncthreads();
    for (int i = bstart + t; i < bend; i += 256)
        atomicAdd(&sdeg[pairs[i] & 127], 1);
    __syncthreads();
    if (t < 128) stmp[t] = sdeg[t];
    __syncthreads();
    #pragma unroll
    for (int off = 1; off < 128; off <<= 1) {
        int v = (t < 128 && t >= off) ? stmp[t - off] : 0;
        __syncthreads();
        if (t < 128) stmp[t] += v;
        __syncthreads();
    }
    if (t < 128) {
        int excl = stmp[t] - sdeg[t];
        scur[t] = excl;
        int node = node0 + t;
        if (node < n) rs[node] = bstart + excl;
    }
    if (b == (int)gridDim.x - 1 && t == 0) rs[n] = e;
    __syncthreads();
    for (int i = bstart + t; i < bend; i += 256) {
        unsigned int u = pairs[i];
        int l = (int)(u & 127);
        int p = atomicAdd(&scur[l], 1);
        csr[bstart + p] = (int)(u >> BSH);
    }
}

// ---------------- layer-1 gather-aggregate (bf16 rows, fp32 accum, bf16 out) ----------------
__global__ void k_agg1(const u16* __restrict__ xb, const int* __restrict__ rs,
                       const int* __restrict__ csr, u16* __restrict__ hnb, int n) {
    int wid = (blockIdx.x * blockDim.x + threadIdx.x) >> 6;
    int lane = threadIdx.x & 63;
    if (wid >= n) return;
    int chunk = lane & 15;
    int quad = lane >> 4;
    int start = rs[wid];
    int deg = rs[wid + 1] - start;
    float inv = 1.0f / (1.0f + (float)deg);
    const int* nb = csr + start;
    float acc[8] = {};
    int k = quad;
    for (; k + 4 < deg; k += 8) {
        int s0 = nb[k], s1 = nb[k + 4];
        uint4 u0 = *(const uint4*)(xb + (size_t)s0 * 128 + chunk * 8);
        uint4 u1 = *(const uint4*)(xb + (size_t)s1 * 128 + chunk * 8);
        acc[0] += bflo(u0.x); acc[1] += bfhi(u0.x);
        acc[2] += bflo(u0.y); acc[3] += bfhi(u0.y);
        acc[4] += bflo(u0.z); acc[5] += bfhi(u0.z);
        acc[6] += bflo(u0.w); acc[7] += bfhi(u0.w);
        acc[0] += bflo(u1.x); acc[1] += bfhi(u1.x);
        acc[2] += bflo(u1.y); acc[3] += bfhi(u1.y);
        acc[4] += bflo(u1.z); acc[5] += bfhi(u1.z);
        acc[6] += bflo(u1.w); acc[7] += bfhi(u1.w);
    }
    if (k < deg) {
        int s = nb[k];
        uint4 u = *(const uint4*)(xb + (size_t)s * 128 + chunk * 8);
        acc[0] += bflo(u.x); acc[1] += bfhi(u.x);
        acc[2] += bflo(u.y); acc[3] += bfhi(u.y);
        acc[4] += bflo(u.z); acc[5] += bfhi(u.z);
        acc[6] += bflo(u.w); acc[7] += bfhi(u.w);
    }
    #pragma unroll
    for (int t = 0; t < 8; ++t) {
        acc[t] += __shfl_xor(acc[t], 16);
        acc[t] += __shfl_xor(acc[t], 32);
    }
    if (quad == 0) {
        uint4 u = *(const uint4*)(xb + (size_t)wid * 128 + chunk * 8);  // self
        acc[0] += bflo(u.x); acc[1] += bfhi(u.x);
        acc[2] += bflo(u.y); acc[3] += bfhi(u.y);
        acc[4] += bflo(u.z); acc[5] += bfhi(u.z);
        acc[6] += bflo(u.w); acc[7] += bfhi(u.w);
        uint4 o;
        o.x = packbf2(acc[0] * inv, acc[1] * inv);
        o.y = packbf2(acc[2] * inv, acc[3] * inv);
        o.z = packbf2(acc[4] * inv, acc[5] * inv);
        o.w = packbf2(acc[6] * inv, acc[7] * inv);
        *(uint4*)(hnb + (size_t)wid * 128 + chunk * 8) = o;
    }
}

// ---------------- MFMA GEMM1: h1b = relu([xb|hnb] @ W1cat + b1), bf16 out ----------------
__launch_bounds__(256)
__global__ void k_gemm1_mfma(const u16* __restrict__ xb, const u16* hnb,
                             const u16* __restrict__ W1t, const float* __restrict__ b1,
                             u16* h1b, int n) {
    __shared__ u16 As[128 * 32];
    __shared__ u16 Bs[128 * 32];
    int tid = threadIdx.x;
    int lane = tid & 63;
    int wave = tid >> 6;
    int wr = wave >> 1, wc = wave & 1;
    int row0 = blockIdx.x * 128;
    int srow = tid >> 2;
    int scol = (tid & 3) * 8;
    int m = lane & 15;
    int q = lane >> 4;

    f32x4 zero = {0.f, 0.f, 0.f, 0.f};
    f32x4 acc[4][4];
    #pragma unroll
    for (int i = 0; i < 4; ++i)
        #pragma unroll
        for (int j = 0; j < 4; ++j) acc[i][j] = zero;

    for (int kb = 0; kb < 8; ++kb) {
        const u16* Asrc = (kb < 4) ? xb : hnb;
        int kbase = (kb & 3) * 32;
        int krowB = kb * 32;
        #pragma unroll
        for (int t = 0; t < 2; ++t) {
            int gr = row0 + t * 64 + srow;
            if (gr >= n) gr = n - 1;
            GLDS16(Asrc + (size_t)gr * 128 + kbase + scol, As + t * 2048 + wave * 512);
        }
        #pragma unroll
        for (int t = 0; t < 2; ++t) {
            int nn = t * 64 + srow;
            GLDS16(W1t + (size_t)nn * 256 + krowB + scol, Bs + t * 2048 + wave * 512);
        }
        __syncthreads();
        #pragma unroll
        for (int i = 0; i < 4; ++i) {
            short8 a = *(const short8*)&As[(wr * 64 + i * 16 + m) * 32 + q * 8];
            #pragma unroll
            for (int j = 0; j < 4; ++j) {
                short8 b = *(const short8*)&Bs[(wc * 64 + j * 16 + m) * 32 + q * 8];
                acc[i][j] = __builtin_amdgcn_mfma_f32_16x16x32_bf16(a, b, acc[i][j], 0, 0, 0);
            }
        }
        __syncthreads();
    }
    #pragma unroll
    for (int i = 0; i < 4; ++i) {
        int grow = row0 + wr * 64 + i * 16 + q * 4;
        #pragma unroll
        for (int j = 0; j < 4; ++j) {
            int col = wc * 64 + j * 16 + m;
            float bias = b1[col];
            #pragma unroll
            for (int r = 0; r < 4; ++r) {
                int gr = grow + r;
                if (gr < n) h1b[(size_t)gr * 128 + col] = f2bf(fmaxf(acc[i][j][r] + bias, 0.f));
            }
        }
    }
}

// ---------------- MFMA GEMM2: qp = h1b @ [Ws2|Wn2] (cols 0..63=q, 64..127=p) ----------------
__launch_bounds__(256)
__global__ void k_gemm2_mfma(const u16* __restrict__ h1b, const u16* __restrict__ W2t,
                             u16* __restrict__ qp, int n) {
    __shared__ u16 As[128 * 32];
    __shared__ u16 Bs[128 * 32];
    int tid = threadIdx.x;
    int lane = tid & 63;
    int wave = tid >> 6;
    int wr = wave >> 1, wc = wave & 1;
    int row0 = blockIdx.x * 128;
    int srow = tid >> 2;
    int scol = (tid & 3) * 8;
    int m = lane & 15;
    int q = lane >> 4;

    f32x4 zero = {0.f, 0.f, 0.f, 0.f};
    f32x4 acc[4][4];
    #pragma unroll
    for (int i = 0; i < 4; ++i)
        #pragma unroll
        for (int j = 0; j < 4; ++j) acc[i][j] = zero;

    for (int kb = 0; kb < 4; ++kb) {
        int kbase = kb * 32;
        #pragma unroll
        for (int t = 0; t < 2; ++t) {
            int gr = row0 + t * 64 + srow;
            if (gr >= n) gr = n - 1;
            GLDS16(h1b + (size_t)gr * 128 + kbase + scol, As + t * 2048 + wave * 512);
        }
        #pragma unroll
        for (int t = 0; t < 2; ++t) {
            int nn = t * 64 + srow;
            GLDS16(W2t + (size_t)nn * 128 + kbase + scol, Bs + t * 2048 + wave * 512);
        }
        __syncthreads();
        #pragma unroll
        for (int i = 0; i < 4; ++i) {
            short8 a = *(const short8*)&As[(wr * 64 + i * 16 + m) * 32 + q * 8];
            #pragma unroll
            for (int j = 0; j < 4; ++j) {
                short8 b = *(const short8*)&Bs[(wc * 64 + j * 16 + m) * 32 + q * 8];
                acc[i][j] = __builtin_amdgcn_mfma_f32_16x16x32_bf16(a, b, acc[i][j], 0, 0, 0);
            }
        }
        __syncthreads();
    }
    #pragma unroll
    for (int i = 0; i < 4; ++i) {
        int grow = row0 + wr * 64 + i * 16 + q * 4;
        #pragma unroll
        for (int j = 0; j < 4; ++j) {
            int col = wc * 64 + j * 16 + m;
            #pragma unroll
            for (int r = 0; r < 4; ++r) {
                int gr = grow + r;
                if (gr < n) qp[(size_t)gr * 128 + col] = f2bf(acc[i][j][r]);
            }
        }
    }
}

// ---------------- layer-2 gather-aggregate + epilogue ----------------
__global__ void k_agg2(const u16* __restrict__ qp, const int* __restrict__ rs,
                       const int* __restrict__ csr, const float* __restrict__ b2,
                       float* __restrict__ out, int n) {
    int wid = (blockIdx.x * blockDim.x + threadIdx.x) >> 6;
    int lane = threadIdx.x & 63;
    if (wid >= n) return;
    int chunk = lane & 7;
    int oct = lane >> 3;
    int start = rs[wid];
    int deg = rs[wid + 1] - start;
    float inv = 1.0f / (1.0f + (float)deg);
    const int* nb = csr + start;
    float acc[8] = {};
    for (int k = oct; k < deg; k += 8) {
        int s = nb[k];
        uint4 u = *(const uint4*)(qp + (size_t)s * 128 + 64 + chunk * 8);
        acc[0] += bflo(u.x); acc[1] += bfhi(u.x);
        acc[2] += bflo(u.y); acc[3] += bfhi(u.y);
        acc[4] += bflo(u.z); acc[5] += bfhi(u.z);
        acc[6] += bflo(u.w); acc[7] += bfhi(u.w);
    }
    #pragma unroll
    for (int t = 0; t < 8; ++t) {
        acc[t] += __shfl_xor(acc[t], 8);
        acc[t] += __shfl_xor(acc[t], 16);
        acc[t] += __shfl_xor(acc[t], 32);
    }
    if (oct == 0) {
        uint4 up = *(const uint4*)(qp + (size_t)wid * 128 + 64 + chunk * 8); // self p
        uint4 uq = *(const uint4*)(qp + (size_t)wid * 128 + chunk * 8);      // q
        float o[8];
        o[0] = (acc[0] + bflo(up.x)) * inv + bflo(uq.x);
        o[1] = (acc[1] + bfhi(up.x)) * inv + bfhi(uq.x);
        o[2] = (acc[2] + bflo(up.y)) * inv + bflo(uq.y);
        o[3] = (acc[3] + bfhi(up.y)) * inv + bfhi(uq.y);
        o[4] = (acc[4] + bflo(up.z)) * inv + bflo(uq.z);
        o[5] = (acc[5] + bfhi(up.z)) * inv + bfhi(uq.z);
        o[6] = (acc[6] + bflo(up.w)) * inv + bflo(uq.w);
        o[7] = (acc[7] + bfhi(up.w)) * inv + bfhi(uq.w);
        float* op = out + (size_t)wid * 64 + chunk * 8;
        const float* bp = b2 + chunk * 8;
        *(float4*)(op + 0) = make_float4(o[0] + bp[0], o[1] + bp[1], o[2] + bp[2], o[3] + bp[3]);
        *(float4*)(op + 4) = make_float4(o[4] + bp[4], o[5] + bp[5], o[6] + bp[6], o[7] + bp[7]);
    }
}

extern "C" void kernel_launch(void* const* d_in, const int* in_sizes, int n_in,
                              void* d_out, int out_size, void* d_ws, size_t ws_size,
                              hipStream_t stream) {
    const float* x   = (const float*)d_in[0];
    const int*   src = (const int*)d_in[1];
    const int*   dst = (const int*)d_in[2];
    const float* Ws1 = (const float*)d_in[3];
    const float* Wn1 = (const float*)d_in[4];
    const float* b1  = (const float*)d_in[5];
    const float* Ws2 = (const float*)d_in[6];
    const float* Wn2 = (const float*)d_in[7];
    const float* b2  = (const float*)d_in[8];
    int n = in_sizes[0] / D_IN;
    int e = in_sizes[1];
    int NB = (n + 127) >> BSH;         // <= 1024 for n <= 131072
    int T = NB * NW;                   // scan length (<= 131072)
    int chunk = (e + NW - 1) / NW;

    char* ws = (char*)d_ws;
    size_t off = 0;
    int* table = (int*)(ws + off); off = align_up(off + (size_t)T * 4, 256);
    int* bsum  = (int*)(ws + off); off = align_up(off + 128 * 4, 256);
    unsigned int* pairs = (unsigned int*)(ws + off); off = align_up(off + (size_t)e * 4, 256);
    int* rs    = (int*)(ws + off); off = align_up(off + (size_t)(n + 1) * 4, 256);
    int* csr   = (int*)(ws + off); off = align_up(off + (size_t)e * 4, 256);
    u16* xb    = (u16*)(ws + off); off = align_up(off + (size_t)n * 128 * 2, 256);
    u16* hnb   = (u16*)(ws + off); off = align_up(off + (size_t)n * 128 * 2, 256);
    u16* qp    = (u16*)(ws + off); off = align_up(off + (size_t)n * 128 * 2, 256);
    u16* W1t   = (u16*)(ws + off); off = align_up(off + (size_t)128 * 256 * 2, 256);
    u16* W2t   = (u16*)(ws + off); off = align_up(off + (size_t)128 * 128 * 2, 256);
    u16* h1b = hnb;   // safe alias: gemm1 reads/writes only its own block rows
    float* outp = (float*)d_out;

    const int B = 256;
    int nblk_scan = (T + 1023) / 1024;   // <= 128
    k_prep<<<(n * 32 + B - 1) / B, B, 0, stream>>>(x, xb, n * 32,
                                                   Ws1, Wn1, Ws2, Wn2, W1t, W2t);
    k_whist<<<NW, B, 0, stream>>>(dst, table, e, NB, chunk);
    k_scan1<<<nblk_scan, 256, 0, stream>>>(table, bsum, T);
    k_scan2<<<1, 128, 0, stream>>>(bsum, nblk_scan);
    k_scan3<<<(T + B - 1) / B, B, 0, stream>>>(table, bsum, T);
    k_wplace<<<NW, B, 0, stream>>>(src, dst, table, pairs, e, NB, chunk);
    k_bucket<<<NB, 256, 0, stream>>>(pairs, table, rs, csr, n, e, NB);
    k_agg1<<<(n + 3) / 4, B, 0, stream>>>(xb, rs, csr, hnb, n);
    k_gemm1_mfma<<<(n + 127) / 128, 256, 0, stream>>>(xb, hnb, W1t, b1, h1b, n);
    k_gemm2_mfma<<<(n + 127) / 128, 256, 0, stream>>>(h1b, W2t, qp, n);
    k_agg2<<<(n + 3) / 4, B, 0, stream>>>(qp, rs, csr, b2, outp, n);
}

// Round 7
// 276.743 us; speedup vs baseline: 1.7896x; 1.0130x over previous
//
#include <hip/hip_runtime.h>

#define D_IN 128
#define BSH 7              // nodes per bucket = 128
#define NW  128            // binning workgroups
#define H1P 136            // padded LDS pitch for h1 tile (bf16 elems)

typedef unsigned short u16;
typedef __attribute__((ext_vector_type(8))) short short8;
typedef __attribute__((ext_vector_type(4))) float f32x4;
typedef __attribute__((ext_vector_type(2))) float f32x2;

static inline size_t align_up(size_t v, size_t a) { return (v + a - 1) & ~(a - 1); }

__device__ inline u16 f2bf(float f) {
    union { float f; unsigned int u; } c; c.f = f;
    unsigned int u = c.u;
    return (u16)((u + 0x7fffu + ((u >> 16) & 1u)) >> 16);   // RNE
}
__device__ inline unsigned int packbf2(float lo, float hi) {
    return (unsigned int)f2bf(lo) | ((unsigned int)f2bf(hi) << 16);
}
// bf16x2 (packed in u32) -> float2, shift/and only (2 VALU), enables v_pk_add_f32 accum
__device__ inline f32x2 bf2f2(unsigned int u) {
    union { unsigned int u; float f; } lo, hi;
    lo.u = u << 16;
    hi.u = u & 0xffff0000u;
    f32x2 r; r.x = lo.f; r.y = hi.f;
    return r;
}

#define GLDS16(gp, lp) \
    __builtin_amdgcn_global_load_lds((const __attribute__((address_space(1))) void*)(gp), \
                                     (__attribute__((address_space(3))) void*)(lp), 16, 0, 0)

// ---------------- prep: cast x->bf16 + pack weights + per-WG bucket hist ----------------
__global__ void k_prep(const float* __restrict__ x, u16* __restrict__ xb, int total4,
                       const float* __restrict__ Ws1, const float* __restrict__ Wn1,
                       const float* __restrict__ Ws2, const float* __restrict__ Wn2,
                       u16* __restrict__ W1t, u16* __restrict__ W2t,
                       const int* __restrict__ dst, int* __restrict__ table,
                       int e, int NB, int chunk) {
    __shared__ int h[1024];
    int t = threadIdx.x;
    int i = blockIdx.x * blockDim.x + t;
    if (i < total4) {
        float4 v = ((const float4*)x)[i];
        uint2 o;
        o.x = packbf2(v.x, v.y);
        o.y = packbf2(v.z, v.w);
        *(uint2*)&xb[(size_t)i * 4] = o;
    }
    if (i < 128 * 256) {
        int nn = i >> 8, kk = i & 255;
        float v = (kk < 128) ? Ws1[kk * 128 + nn] : Wn1[(kk - 128) * 128 + nn];
        W1t[i] = f2bf(v);
    }
    if (i < 128 * 128) {
        int nn = i >> 7, kk = i & 127;
        float v = (nn < 64) ? Ws2[kk * 64 + nn] : Wn2[kk * 64 + (nn - 64)];
        W2t[i] = f2bf(v);
    }
    // first NW blocks additionally build the per-WG bucket histogram
    int w = blockIdx.x;
    if (w < NW) {
        for (int j = t; j < 1024; j += 256) h[j] = 0;
        __syncthreads();
        int lo = w * chunk;
        int hi = lo + chunk; if (hi > e) hi = e;
        for (int k = lo + t; k < hi; k += 256)
            atomicAdd(&h[dst[k] >> BSH], 1);
        __syncthreads();
        for (int b = t; b < NB; b += 256)
            table[b * NW + w] = h[b];
    }
}

// ---------------- scan 1: per-block (1024) exclusive scan in place + block sums ----------------
__global__ void k_scan1(int* __restrict__ a, int* __restrict__ bsum, int T) {
    __shared__ int sd[256];
    int t = threadIdx.x;
    int base = blockIdx.x * 1024 + t * 4;
    int v[4]; int s = 0;
    #pragma unroll
    for (int j = 0; j < 4; ++j) { v[j] = (base + j < T) ? a[base + j] : 0; s += v[j]; }
    sd[t] = s;
    __syncthreads();
    #pragma unroll
    for (int off = 1; off < 256; off <<= 1) {
        int x = (t >= off) ? sd[t - off] : 0;
        __syncthreads();
        sd[t] += x;
        __syncthreads();
    }
    int run = sd[t] - s;
    #pragma unroll
    for (int j = 0; j < 4; ++j) {
        if (base + j < T) a[base + j] = run;
        run += v[j];
    }
    if (t == 255) bsum[blockIdx.x] = sd[255];
}

// ---------------- scan 2: single block, exclusive scan of block sums (nb <= 128) ----------------
__global__ void k_scan2(int* __restrict__ bsum, int nb) {
    __shared__ int sd[128];
    int t = threadIdx.x;
    int own = (t < nb) ? bsum[t] : 0;
    sd[t] = own;
    __syncthreads();
    #pragma unroll
    for (int off = 1; off < 128; off <<= 1) {
        int x = (t >= off) ? sd[t - off] : 0;
        __syncthreads();
        sd[t] += x;
        __syncthreads();
    }
    if (t < nb) bsum[t] = sd[t] - own;
}

// ---------------- scan 3: add block offsets ----------------
__global__ void k_scan3(int* __restrict__ a, const int* __restrict__ bsum, int T) {
    int i = blockIdx.x * blockDim.x + threadIdx.x;
    if (i < T) a[i] += bsum[i >> 10];
}

// ---------------- place pairs at private offsets (LDS cursors, no global atomics) ----------------
__global__ void k_wplace(const int* __restrict__ src, const int* __restrict__ dst,
                         const int* __restrict__ table, unsigned int* __restrict__ pairs,
                         int e, int NB, int chunk) {
    __shared__ int cur[1024];
    int w = blockIdx.x;
    int t = threadIdx.x;
    for (int b = t; b < NB; b += 256) cur[b] = table[b * NW + w];
    __syncthreads();
    int lo = w * chunk;
    int hi = lo + chunk; if (hi > e) hi = e;
    for (int i = lo + t; i < hi; i += 256) {
        int d = dst[i];
        int p = atomicAdd(&cur[d >> BSH], 1);
        pairs[p] = ((unsigned int)src[i] << BSH) | (unsigned int)(d & 127);
    }
}

// ---------------- per-bucket: LDS degree+scan, write rs[], place CSR segment ----------------
__global__ void k_bucket(const unsigned int* __restrict__ pairs, const int* __restrict__ table,
                         int* __restrict__ rs, int* __restrict__ csr, int n, int e, int NB) {
    __shared__ int sdeg[128];
    __shared__ int stmp[128];
    __shared__ int scur[128];
    int b = blockIdx.x;
    int t = threadIdx.x;
    int node0 = b << BSH;
    int bstart = table[b * NW];
    int bend = (b + 1 < NB) ? table[(b + 1) * NW] : e;
    if (t < 128) sdeg[t] = 0;
    __syncthreads();
    for (int i = bstart + t; i < bend; i += 256)
        atomicAdd(&sdeg[pairs[i] & 127], 1);
    __syncthreads();
    if (t < 128) stmp[t] = sdeg[t];
    __syncthreads();
    #pragma unroll
    for (int off = 1; off < 128; off <<= 1) {
        int v = (t < 128 && t >= off) ? stmp[t - off] : 0;
        __syncthreads();
        if (t < 128) stmp[t] += v;
        __syncthreads();
    }
    if (t < 128) {
        int excl = stmp[t] - sdeg[t];
        scur[t] = excl;
        int node = node0 + t;
        if (node < n) rs[node] = bstart + excl;
    }
    if (b == (int)gridDim.x - 1 && t == 0) rs[n] = e;
    __syncthreads();
    for (int i = bstart + t; i < bend; i += 256) {
        unsigned int u = pairs[i];
        int l = (int)(u & 127);
        int p = atomicAdd(&scur[l], 1);
        csr[bstart + p] = (int)(u >> BSH);
    }
}

// ---------------- layer-1 gather-aggregate: packed f32x2 accum ----------------
__global__ void k_agg1(const u16* __restrict__ xb, const int* __restrict__ rs,
                       const int* __restrict__ csr, u16* __restrict__ hnb, int n) {
    int wid = (blockIdx.x * blockDim.x + threadIdx.x) >> 6;
    int lane = threadIdx.x & 63;
    if (wid >= n) return;
    int chunk = lane & 15;
    int quad = lane >> 4;
    int start = rs[wid];
    int deg = rs[wid + 1] - start;
    float inv = 1.0f / (1.0f + (float)deg);
    const int* nb = csr + start;
    f32x2 a0 = {0.f, 0.f}, a1 = {0.f, 0.f}, a2 = {0.f, 0.f}, a3 = {0.f, 0.f};
    int k = quad;
    for (; k + 4 < deg; k += 8) {
        int s0 = nb[k], s1 = nb[k + 4];
        uint4 u0 = *(const uint4*)(xb + (size_t)s0 * 128 + chunk * 8);
        uint4 u1 = *(const uint4*)(xb + (size_t)s1 * 128 + chunk * 8);
        a0 += bf2f2(u0.x); a1 += bf2f2(u0.y); a2 += bf2f2(u0.z); a3 += bf2f2(u0.w);
        a0 += bf2f2(u1.x); a1 += bf2f2(u1.y); a2 += bf2f2(u1.z); a3 += bf2f2(u1.w);
    }
    if (k < deg) {
        int s = nb[k];
        uint4 u = *(const uint4*)(xb + (size_t)s * 128 + chunk * 8);
        a0 += bf2f2(u.x); a1 += bf2f2(u.y); a2 += bf2f2(u.z); a3 += bf2f2(u.w);
    }
    #pragma unroll
    for (int sh = 16; sh <= 32; sh <<= 1) {
        a0.x += __shfl_xor(a0.x, sh); a0.y += __shfl_xor(a0.y, sh);
        a1.x += __shfl_xor(a1.x, sh); a1.y += __shfl_xor(a1.y, sh);
        a2.x += __shfl_xor(a2.x, sh); a2.y += __shfl_xor(a2.y, sh);
        a3.x += __shfl_xor(a3.x, sh); a3.y += __shfl_xor(a3.y, sh);
    }
    if (quad == 0) {
        uint4 u = *(const uint4*)(xb + (size_t)wid * 128 + chunk * 8);  // self
        a0 += bf2f2(u.x); a1 += bf2f2(u.y); a2 += bf2f2(u.z); a3 += bf2f2(u.w);
        uint4 o;
        o.x = packbf2(a0.x * inv, a0.y * inv);
        o.y = packbf2(a1.x * inv, a1.y * inv);
        o.z = packbf2(a2.x * inv, a2.y * inv);
        o.w = packbf2(a3.x * inv, a3.y * inv);
        *(uint4*)(hnb + (size_t)wid * 128 + chunk * 8) = o;
    }
}

// ---------------- fused MFMA GEMM1+GEMM2 ----------------
// h1 = relu([xb|hnb] @ W1t^T + b1) kept in padded LDS tile; qp = h1 @ W2t^T.
__launch_bounds__(256)
__global__ void k_gemm12(const u16* __restrict__ xb, const u16* __restrict__ hnb,
                         const u16* __restrict__ W1t, const u16* __restrict__ W2t,
                         const float* __restrict__ b1, u16* __restrict__ qp, int n) {
    __shared__ u16 As[128 * 32];
    __shared__ u16 Bs[128 * 32];
    __shared__ u16 h1s[128 * H1P];
    int tid = threadIdx.x;
    int lane = tid & 63;
    int wave = tid >> 6;
    int wr = wave >> 1, wc = wave & 1;
    int row0 = blockIdx.x * 128;
    int srow = tid >> 2;
    int scol = (tid & 3) * 8;
    int m = lane & 15;
    int q = lane >> 4;

    f32x4 zero = {0.f, 0.f, 0.f, 0.f};
    f32x4 acc[4][4];
    #pragma unroll
    for (int i = 0; i < 4; ++i)
        #pragma unroll
        for (int j = 0; j < 4; ++j) acc[i][j] = zero;

    // ---- GEMM1: K = 256 over [xb | hnb] ----
    for (int kb = 0; kb < 8; ++kb) {
        const u16* Asrc = (kb < 4) ? xb : hnb;
        int kbase = (kb & 3) * 32;
        int krowB = kb * 32;
        #pragma unroll
        for (int t = 0; t < 2; ++t) {
            int gr = row0 + t * 64 + srow;
            if (gr >= n) gr = n - 1;
            GLDS16(Asrc + (size_t)gr * 128 + kbase + scol, As + t * 2048 + wave * 512);
        }
        #pragma unroll
        for (int t = 0; t < 2; ++t) {
            int nn = t * 64 + srow;
            GLDS16(W1t + (size_t)nn * 256 + krowB + scol, Bs + t * 2048 + wave * 512);
        }
        __syncthreads();
        #pragma unroll
        for (int i = 0; i < 4; ++i) {
            short8 a = *(const short8*)&As[(wr * 64 + i * 16 + m) * 32 + q * 8];
            #pragma unroll
            for (int j = 0; j < 4; ++j) {
                short8 b = *(const short8*)&Bs[(wc * 64 + j * 16 + m) * 32 + q * 8];
                acc[i][j] = __builtin_amdgcn_mfma_f32_16x16x32_bf16(a, b, acc[i][j], 0, 0, 0);
            }
        }
        __syncthreads();
    }
    // ---- epilogue1: bias+relu -> h1s (padded pitch; row stride = 4 banks -> 2-way only) ----
    #pragma unroll
    for (int i = 0; i < 4; ++i) {
        int rl = wr * 64 + i * 16 + q * 4;
        #pragma unroll
        for (int j = 0; j < 4; ++j) {
            int col = wc * 64 + j * 16 + m;
            float bias = b1[col];
            #pragma unroll
            for (int r = 0; r < 4; ++r)
                h1s[(rl + r) * H1P + col] = f2bf(fmaxf(acc[i][j][r] + bias, 0.f));
        }
    }
    #pragma unroll
    for (int i = 0; i < 4; ++i)
        #pragma unroll
        for (int j = 0; j < 4; ++j) acc[i][j] = zero;
    __syncthreads();

    // ---- GEMM2: K = 128 over h1s (LDS), B = W2t staged ----
    for (int kb = 0; kb < 4; ++kb) {
        int kbase = kb * 32;
        #pragma unroll
        for (int t = 0; t < 2; ++t) {
            int nn = t * 64 + srow;
            GLDS16(W2t + (size_t)nn * 128 + kbase + scol, Bs + t * 2048 + wave * 512);
        }
        __syncthreads();
        #pragma unroll
        for (int i = 0; i < 4; ++i) {
            short8 a = *(const short8*)&h1s[(wr * 64 + i * 16 + m) * H1P + kbase + q * 8];
            #pragma unroll
            for (int j = 0; j < 4; ++j) {
                short8 b = *(const short8*)&Bs[(wc * 64 + j * 16 + m) * 32 + q * 8];
                acc[i][j] = __builtin_amdgcn_mfma_f32_16x16x32_bf16(a, b, acc[i][j], 0, 0, 0);
            }
        }
        __syncthreads();
    }
    #pragma unroll
    for (int i = 0; i < 4; ++i) {
        int grow = row0 + wr * 64 + i * 16 + q * 4;
        #pragma unroll
        for (int j = 0; j < 4; ++j) {
            int col = wc * 64 + j * 16 + m;
            #pragma unroll
            for (int r = 0; r < 4; ++r) {
                int gr = grow + r;
                if (gr < n) qp[(size_t)gr * 128 + col] = f2bf(acc[i][j][r]);
            }
        }
    }
}

// ---------------- layer-2 gather-aggregate + epilogue (packed accum, 2-deep) ----------------
__global__ void k_agg2(const u16* __restrict__ qp, const int* __restrict__ rs,
                       const int* __restrict__ csr, const float* __restrict__ b2,
                       float* __restrict__ out, int n) {
    int wid = (blockIdx.x * blockDim.x + threadIdx.x) >> 6;
    int lane = threadIdx.x & 63;
    if (wid >= n) return;
    int chunk = lane & 7;
    int oct = lane >> 3;
    int start = rs[wid];
    int deg = rs[wid + 1] - start;
    float inv = 1.0f / (1.0f + (float)deg);
    const int* nb = csr + start;
    f32x2 a0 = {0.f, 0.f}, a1 = {0.f, 0.f}, a2 = {0.f, 0.f}, a3 = {0.f, 0.f};
    int k = oct;
    for (; k + 8 < deg; k += 16) {
        int s0 = nb[k], s1 = nb[k + 8];
        uint4 u0 = *(const uint4*)(qp + (size_t)s0 * 128 + 64 + chunk * 8);
        uint4 u1 = *(const uint4*)(qp + (size_t)s1 * 128 + 64 + chunk * 8);
        a0 += bf2f2(u0.x); a1 += bf2f2(u0.y); a2 += bf2f2(u0.z); a3 += bf2f2(u0.w);
        a0 += bf2f2(u1.x); a1 += bf2f2(u1.y); a2 += bf2f2(u1.z); a3 += bf2f2(u1.w);
    }
    if (k < deg) {
        int s = nb[k];
        uint4 u = *(const uint4*)(qp + (size_t)s * 128 + 64 + chunk * 8);
        a0 += bf2f2(u.x); a1 += bf2f2(u.y); a2 += bf2f2(u.z); a3 += bf2f2(u.w);
    }
    #pragma unroll
    for (int sh = 8; sh <= 32; sh <<= 1) {
        a0.x += __shfl_xor(a0.x, sh); a0.y += __shfl_xor(a0.y, sh);
        a1.x += __shfl_xor(a1.x, sh); a1.y += __shfl_xor(a1.y, sh);
        a2.x += __shfl_xor(a2.x, sh); a2.y += __shfl_xor(a2.y, sh);
        a3.x += __shfl_xor(a3.x, sh); a3.y += __shfl_xor(a3.y, sh);
    }
    if (oct == 0) {
        uint4 up = *(const uint4*)(qp + (size_t)wid * 128 + 64 + chunk * 8); // self p
        uint4 uq = *(const uint4*)(qp + (size_t)wid * 128 + chunk * 8);      // q
        f32x2 p0 = bf2f2(up.x), p1 = bf2f2(up.y), p2 = bf2f2(up.z), p3 = bf2f2(up.w);
        f32x2 q0 = bf2f2(uq.x), q1 = bf2f2(uq.y), q2 = bf2f2(uq.z), q3 = bf2f2(uq.w);
        float o[8];
        o[0] = (a0.x + p0.x) * inv + q0.x;
        o[1] = (a0.y + p0.y) * inv + q0.y;
        o[2] = (a1.x + p1.x) * inv + q1.x;
        o[3] = (a1.y + p1.y) * inv + q1.y;
        o[4] = (a2.x + p2.x) * inv + q2.x;
        o[5] = (a2.y + p2.y) * inv + q2.y;
        o[6] = (a3.x + p3.x) * inv + q3.x;
        o[7] = (a3.y + p3.y) * inv + q3.y;
        float* op = out + (size_t)wid * 64 + chunk * 8;
        const float* bp = b2 + chunk * 8;
        *(float4*)(op + 0) = make_float4(o[0] + bp[0], o[1] + bp[1], o[2] + bp[2], o[3] + bp[3]);
        *(float4*)(op + 4) = make_float4(o[4] + bp[4], o[5] + bp[5], o[6] + bp[6], o[7] + bp[7]);
    }
}

extern "C" void kernel_launch(void* const* d_in, const int* in_sizes, int n_in,
                              void* d_out, int out_size, void* d_ws, size_t ws_size,
                              hipStream_t stream) {
    const float* x   = (const float*)d_in[0];
    const int*   src = (const int*)d_in[1];
    const int*   dst = (const int*)d_in[2];
    const float* Ws1 = (const float*)d_in[3];
    const float* Wn1 = (const float*)d_in[4];
    const float* b1  = (const float*)d_in[5];
    const float* Ws2 = (const float*)d_in[6];
    const float* Wn2 = (const float*)d_in[7];
    const float* b2  = (const float*)d_in[8];
    int n = in_sizes[0] / D_IN;
    int e = in_sizes[1];
    int NB = (n + 127) >> BSH;
    int T = NB * NW;
    int chunk = (e + NW - 1) / NW;

    char* ws = (char*)d_ws;
    size_t off = 0;
    int* table = (int*)(ws + off); off = align_up(off + (size_t)T * 4, 256);
    int* bsum  = (int*)(ws + off); off = align_up(off + 128 * 4, 256);
    unsigned int* pairs = (unsigned int*)(ws + off); off = align_up(off + (size_t)e * 4, 256);
    int* rs    = (int*)(ws + off); off = align_up(off + (size_t)(n + 1) * 4, 256);
    int* csr   = (int*)(ws + off); off = align_up(off + (size_t)e * 4, 256);
    u16* xb    = (u16*)(ws + off); off = align_up(off + (size_t)n * 128 * 2, 256);
    u16* hnb   = (u16*)(ws + off); off = align_up(off + (size_t)n * 128 * 2, 256);
    u16* qp    = (u16*)(ws + off); off = align_up(off + (size_t)n * 128 * 2, 256);
    u16* W1t   = (u16*)(ws + off); off = align_up(off + (size_t)128 * 256 * 2, 256);
    u16* W2t   = (u16*)(ws + off); off = align_up(off + (size_t)128 * 128 * 2, 256);
    float* outp = (float*)d_out;

    const int B = 256;
    int nblk_scan = (T + 1023) / 1024;   // <= 128
    k_prep<<<(n * 32 + B - 1) / B, B, 0, stream>>>(x, xb, n * 32,
                                                   Ws1, Wn1, Ws2, Wn2, W1t, W2t,
                                                   dst, table, e, NB, chunk);
    k_scan1<<<nblk_scan, 256, 0, stream>>>(table, bsum, T);
    k_scan2<<<1, 128, 0, stream>>>(bsum, nblk_scan);
    k_scan3<<<(T + B - 1) / B, B, 0, stream>>>(table, bsum, T);
    k_wplace<<<NW, B, 0, stream>>>(src, dst, table, pairs, e, NB, chunk);
    k_bucket<<<NB, 256, 0, stream>>>(pairs, table, rs, csr, n, e, NB);
    k_agg1<<<(n + 3) / 4, B, 0, stream>>>(xb, rs, csr, hnb, n);
    k_gemm12<<<(n + 127) / 128, 256, 0, stream>>>(xb, hnb, W1t, W2t, b1, qp, n);
    k_agg2<<<(n + 3) / 4, B, 0, stream>>>(qp, rs, csr, b2, outp, n);
}

// Round 8
// 270.895 us; speedup vs baseline: 1.8282x; 1.0216x over previous
//
#include <hip/hip_runtime.h>

#define D_IN 128
#define BSH 7              // nodes per bucket = 128
#define NW  128            // binning workgroups
#define H1P 136            // padded LDS pitch for h1 tile (bf16 elems)
#define SLICE 2048         // LDS pairs-slice capacity in k_bucket

#if defined(__has_builtin)
#if __has_builtin(__builtin_amdgcn_cvt_pk_f32_fp8)
#define HAVE_FP8 1
#endif
#endif
#ifndef HAVE_FP8
#define HAVE_FP8 0
#endif

typedef unsigned short u16;
typedef unsigned char u8;
typedef __attribute__((ext_vector_type(8))) short short8;
typedef __attribute__((ext_vector_type(4))) float f32x4;
typedef __attribute__((ext_vector_type(2))) float f32x2;

static inline size_t align_up(size_t v, size_t a) { return (v + a - 1) & ~(a - 1); }

__device__ inline u16 f2bf(float f) {
    union { float f; unsigned int u; } c; c.f = f;
    unsigned int u = c.u;
    return (u16)((u + 0x7fffu + ((u >> 16) & 1u)) >> 16);   // RNE
}
__device__ inline unsigned int packbf2(float lo, float hi) {
    return (unsigned int)f2bf(lo) | ((unsigned int)f2bf(hi) << 16);
}
__device__ inline f32x2 bf2f2(unsigned int u) {
    union { unsigned int u; float f; } lo, hi;
    lo.u = u << 16;
    hi.u = u & 0xffff0000u;
    f32x2 r; r.x = lo.f; r.y = hi.f;
    return r;
}
// f32 -> OCP e4m3fn (RNE, saturate to 448, denormal-correct)
__device__ inline unsigned int f2fp8(float f) {
    float m = fabsf(f);
    m = fminf(m, 448.0f);
    unsigned int s = (__float_as_uint(f) >> 31) << 7;
    if (m < 0.015625f) {                       // < 2^-6 : denormal codes 0..7 (and 8 on round-up)
        int c = (int)rintf(m * 512.0f);
        return s | (unsigned int)c;
    }
    unsigned int au = __float_as_uint(m);
    au += 0x7FFFF + ((au >> 20) & 1);          // RNE to 3 mantissa bits
    int e = (int)(au >> 23) - 127;
    int mant = (int)(au >> 20) & 7;
    int code = ((e + 7) << 3) | mant;
    if (code > 0x7E) code = 0x7E;              // clamp to 448
    return s | (unsigned int)code;
}

#define GLDS16(gp, lp) \
    __builtin_amdgcn_global_load_lds((const __attribute__((address_space(1))) void*)(gp), \
                                     (__attribute__((address_space(3))) void*)(lp), 16, 0, 0)

// ---------------- prep: cast x->bf16 + x->fp8 + pack weights + per-WG bucket hist ----------------
__global__ void k_prep(const float* __restrict__ x, u16* __restrict__ xb,
                       unsigned int* __restrict__ xf8, int total4,
                       const float* __restrict__ Ws1, const float* __restrict__ Wn1,
                       const float* __restrict__ Ws2, const float* __restrict__ Wn2,
                       u16* __restrict__ W1t, u16* __restrict__ W2t,
                       const int* __restrict__ dst, int* __restrict__ table,
                       int e, int NB, int chunk) {
    __shared__ int h[1024];
    int t = threadIdx.x;
    int i = blockIdx.x * blockDim.x + t;
    if (i < total4) {
        float4 v = ((const float4*)x)[i];
        uint2 o;
        o.x = packbf2(v.x, v.y);
        o.y = packbf2(v.z, v.w);
        *(uint2*)&xb[(size_t)i * 4] = o;
        xf8[i] = f2fp8(v.x) | (f2fp8(v.y) << 8) | (f2fp8(v.z) << 16) | (f2fp8(v.w) << 24);
    }
    if (i < 128 * 256) {
        int nn = i >> 8, kk = i & 255;
        float v = (kk < 128) ? Ws1[kk * 128 + nn] : Wn1[(kk - 128) * 128 + nn];
        W1t[i] = f2bf(v);
    }
    if (i < 128 * 128) {
        int nn = i >> 7, kk = i & 127;
        float v = (nn < 64) ? Ws2[kk * 64 + nn] : Wn2[kk * 64 + (nn - 64)];
        W2t[i] = f2bf(v);
    }
    int w = blockIdx.x;
    if (w < NW) {
        for (int j = t; j < 1024; j += 256) h[j] = 0;
        __syncthreads();
        int lo = w * chunk;
        int hi = lo + chunk; if (hi > e) hi = e;
        for (int k = lo + t; k < hi; k += 256)
            atomicAdd(&h[dst[k] >> BSH], 1);
        __syncthreads();
        for (int b = t; b < NB; b += 256)
            table[b * NW + w] = h[b];
    }
}

// ---------------- scan 1: per-block (1024) exclusive scan in place + block sums ----------------
__global__ void k_scan1(int* __restrict__ a, int* __restrict__ bsum, int T) {
    __shared__ int sd[256];
    int t = threadIdx.x;
    int base = blockIdx.x * 1024 + t * 4;
    int v[4]; int s = 0;
    #pragma unroll
    for (int j = 0; j < 4; ++j) { v[j] = (base + j < T) ? a[base + j] : 0; s += v[j]; }
    sd[t] = s;
    __syncthreads();
    #pragma unroll
    for (int off = 1; off < 256; off <<= 1) {
        int x = (t >= off) ? sd[t - off] : 0;
        __syncthreads();
        sd[t] += x;
        __syncthreads();
    }
    int run = sd[t] - s;
    #pragma unroll
    for (int j = 0; j < 4; ++j) {
        if (base + j < T) a[base + j] = run;
        run += v[j];
    }
    if (t == 255) bsum[blockIdx.x] = sd[255];
}

// ---------------- place pairs at private offsets (local bsum scan; LDS cursors) ----------------
__global__ void k_wplace(const int* __restrict__ src, const int* __restrict__ dst,
                         const int* __restrict__ table, const int* __restrict__ bsum,
                         unsigned int* __restrict__ pairs,
                         int e, int NB, int chunk, int nblk) {
    __shared__ int cur[1024];
    __shared__ int bscan[128];
    int w = blockIdx.x;
    int t = threadIdx.x;
    int own = 0;
    if (t < 128) {
        own = (t < nblk) ? bsum[t] : 0;
        bscan[t] = own;
    }
    __syncthreads();
    #pragma unroll
    for (int off = 1; off < 128; off <<= 1) {
        int v = (t < 128 && t >= off) ? bscan[t - off] : 0;
        __syncthreads();
        if (t < 128) bscan[t] += v;
        __syncthreads();
    }
    if (t < 128) bscan[t] -= own;   // exclusive
    __syncthreads();
    for (int b = t; b < NB; b += 256) {
        int idx = b * NW + w;
        cur[b] = table[idx] + bscan[idx >> 10];
    }
    __syncthreads();
    int lo = w * chunk;
    int hi = lo + chunk; if (hi > e) hi = e;
    for (int i = lo + t; i < hi; i += 256) {
        int d = dst[i];
        int p = atomicAdd(&cur[d >> BSH], 1);
        pairs[p] = ((unsigned int)src[i] << BSH) | (unsigned int)(d & 127);
    }
}

// ---------------- per-bucket: LDS slice, degree+scan, write rs[], place CSR ----------------
__global__ void k_bucket(const unsigned int* __restrict__ pairs, const int* __restrict__ table,
                         const int* __restrict__ bsum,
                         int* __restrict__ rs, int* __restrict__ csr,
                         int n, int e, int NB, int nblk) {
    __shared__ int sdeg[128];
    __shared__ int stmp[128];
    __shared__ int scur[128];
    __shared__ int bscan[128];
    __shared__ unsigned int ps[SLICE];
    int b = blockIdx.x;
    int t = threadIdx.x;
    int node0 = b << BSH;
    int own = 0;
    if (t < 128) {
        own = (t < nblk) ? bsum[t] : 0;
        bscan[t] = own;
    }
    if (t < 128) sdeg[t] = 0;
    __syncthreads();
    #pragma unroll
    for (int off = 1; off < 128; off <<= 1) {
        int v = (t < 128 && t >= off) ? bscan[t - off] : 0;
        __syncthreads();
        if (t < 128) bscan[t] += v;
        __syncthreads();
    }
    if (t < 128) bscan[t] -= own;
    __syncthreads();
    int i0 = b * NW;
    int bstart = table[i0] + bscan[i0 >> 10];
    int bend;
    if (b + 1 < NB) {
        int i1 = (b + 1) * NW;
        bend = table[i1] + bscan[i1 >> 10];
    } else bend = e;
    int len = bend - bstart;
    bool fits = (len <= SLICE);
    if (fits) {
        for (int i = t; i < len; i += 256) {
            unsigned int u = pairs[bstart + i];
            ps[i] = u;
            atomicAdd(&sdeg[u & 127], 1);
        }
    } else {
        for (int i = bstart + t; i < bend; i += 256)
            atomicAdd(&sdeg[pairs[i] & 127], 1);
    }
    __syncthreads();
    if (t < 128) stmp[t] = sdeg[t];
    __syncthreads();
    #pragma unroll
    for (int off = 1; off < 128; off <<= 1) {
        int v = (t < 128 && t >= off) ? stmp[t - off] : 0;
        __syncthreads();
        if (t < 128) stmp[t] += v;
        __syncthreads();
    }
    if (t < 128) {
        int excl = stmp[t] - sdeg[t];
        scur[t] = excl;
        int node = node0 + t;
        if (node < n) rs[node] = bstart + excl;
    }
    if (b == (int)gridDim.x - 1 && t == 0) rs[n] = e;
    __syncthreads();
    if (fits) {
        for (int i = t; i < len; i += 256) {
            unsigned int u = ps[i];
            int p = atomicAdd(&scur[u & 127], 1);
            csr[bstart + p] = (int)(u >> BSH);
        }
    } else {
        for (int i = bstart + t; i < bend; i += 256) {
            unsigned int u = pairs[i];
            int p = atomicAdd(&scur[u & 127], 1);
            csr[bstart + p] = (int)(u >> BSH);
        }
    }
}

// ---------------- layer-1 gather-aggregate: fp8 gather, f32 accum, bf16 out ----------------
__global__ void k_agg1(const u8* __restrict__ xf8, const u16* __restrict__ xb,
                       const int* __restrict__ rs, const int* __restrict__ csr,
                       u16* __restrict__ hnb, int n) {
    int wid = (blockIdx.x * blockDim.x + threadIdx.x) >> 6;
    int lane = threadIdx.x & 63;
    if (wid >= n) return;
    int chunk = lane & 15;
    int quad = lane >> 4;
    int start = rs[wid];
    int deg = rs[wid + 1] - start;
    float inv = 1.0f / (1.0f + (float)deg);
    const int* nb = csr + start;
    f32x2 a0 = {0.f, 0.f}, a1 = {0.f, 0.f}, a2 = {0.f, 0.f}, a3 = {0.f, 0.f};
    int k = quad;
#if HAVE_FP8
    for (; k + 4 < deg; k += 8) {
        int s0 = nb[k], s1 = nb[k + 4];
        uint2 u0 = *(const uint2*)(xf8 + (size_t)s0 * 128 + chunk * 8);
        uint2 u1 = *(const uint2*)(xf8 + (size_t)s1 * 128 + chunk * 8);
        a0 += __builtin_amdgcn_cvt_pk_f32_fp8(u0.x, false);
        a1 += __builtin_amdgcn_cvt_pk_f32_fp8(u0.x, true);
        a2 += __builtin_amdgcn_cvt_pk_f32_fp8(u0.y, false);
        a3 += __builtin_amdgcn_cvt_pk_f32_fp8(u0.y, true);
        a0 += __builtin_amdgcn_cvt_pk_f32_fp8(u1.x, false);
        a1 += __builtin_amdgcn_cvt_pk_f32_fp8(u1.x, true);
        a2 += __builtin_amdgcn_cvt_pk_f32_fp8(u1.y, false);
        a3 += __builtin_amdgcn_cvt_pk_f32_fp8(u1.y, true);
    }
    if (k < deg) {
        int s = nb[k];
        uint2 u = *(const uint2*)(xf8 + (size_t)s * 128 + chunk * 8);
        a0 += __builtin_amdgcn_cvt_pk_f32_fp8(u.x, false);
        a1 += __builtin_amdgcn_cvt_pk_f32_fp8(u.x, true);
        a2 += __builtin_amdgcn_cvt_pk_f32_fp8(u.y, false);
        a3 += __builtin_amdgcn_cvt_pk_f32_fp8(u.y, true);
    }
#else
    for (; k + 4 < deg; k += 8) {
        int s0 = nb[k], s1 = nb[k + 4];
        uint4 u0 = *(const uint4*)(xb + (size_t)s0 * 128 + chunk * 8);
        uint4 u1 = *(const uint4*)(xb + (size_t)s1 * 128 + chunk * 8);
        a0 += bf2f2(u0.x); a1 += bf2f2(u0.y); a2 += bf2f2(u0.z); a3 += bf2f2(u0.w);
        a0 += bf2f2(u1.x); a1 += bf2f2(u1.y); a2 += bf2f2(u1.z); a3 += bf2f2(u1.w);
    }
    if (k < deg) {
        int s = nb[k];
        uint4 u = *(const uint4*)(xb + (size_t)s * 128 + chunk * 8);
        a0 += bf2f2(u.x); a1 += bf2f2(u.y); a2 += bf2f2(u.z); a3 += bf2f2(u.w);
    }
#endif
    #pragma unroll
    for (int sh = 16; sh <= 32; sh <<= 1) {
        a0.x += __shfl_xor(a0.x, sh); a0.y += __shfl_xor(a0.y, sh);
        a1.x += __shfl_xor(a1.x, sh); a1.y += __shfl_xor(a1.y, sh);
        a2.x += __shfl_xor(a2.x, sh); a2.y += __shfl_xor(a2.y, sh);
        a3.x += __shfl_xor(a3.x, sh); a3.y += __shfl_xor(a3.y, sh);
    }
    if (quad == 0) {
        uint4 u = *(const uint4*)(xb + (size_t)wid * 128 + chunk * 8);  // self (bf16)
        a0 += bf2f2(u.x); a1 += bf2f2(u.y); a2 += bf2f2(u.z); a3 += bf2f2(u.w);
        uint4 o;
        o.x = packbf2(a0.x * inv, a0.y * inv);
        o.y = packbf2(a1.x * inv, a1.y * inv);
        o.z = packbf2(a2.x * inv, a2.y * inv);
        o.w = packbf2(a3.x * inv, a3.y * inv);
        *(uint4*)(hnb + (size_t)wid * 128 + chunk * 8) = o;
    }
}

// ---------------- fused MFMA GEMM1+GEMM2 ----------------
__launch_bounds__(256)
__global__ void k_gemm12(const u16* __restrict__ xb, const u16* __restrict__ hnb,
                         const u16* __restrict__ W1t, const u16* __restrict__ W2t,
                         const float* __restrict__ b1, u16* __restrict__ qp, int n) {
    __shared__ u16 As[128 * 32];
    __shared__ u16 Bs[128 * 32];
    __shared__ u16 h1s[128 * H1P];
    int tid = threadIdx.x;
    int lane = tid & 63;
    int wave = tid >> 6;
    int wr = wave >> 1, wc = wave & 1;
    int row0 = blockIdx.x * 128;
    int srow = tid >> 2;
    int scol = (tid & 3) * 8;
    int m = lane & 15;
    int q = lane >> 4;

    f32x4 zero = {0.f, 0.f, 0.f, 0.f};
    f32x4 acc[4][4];
    #pragma unroll
    for (int i = 0; i < 4; ++i)
        #pragma unroll
        for (int j = 0; j < 4; ++j) acc[i][j] = zero;

    for (int kb = 0; kb < 8; ++kb) {
        const u16* Asrc = (kb < 4) ? xb : hnb;
        int kbase = (kb & 3) * 32;
        int krowB = kb * 32;
        #pragma unroll
        for (int t = 0; t < 2; ++t) {
            int gr = row0 + t * 64 + srow;
            if (gr >= n) gr = n - 1;
            GLDS16(Asrc + (size_t)gr * 128 + kbase + scol, As + t * 2048 + wave * 512);
        }
        #pragma unroll
        for (int t = 0; t < 2; ++t) {
            int nn = t * 64 + srow;
            GLDS16(W1t + (size_t)nn * 256 + krowB + scol, Bs + t * 2048 + wave * 512);
        }
        __syncthreads();
        #pragma unroll
        for (int i = 0; i < 4; ++i) {
            short8 a = *(const short8*)&As[(wr * 64 + i * 16 + m) * 32 + q * 8];
            #pragma unroll
            for (int j = 0; j < 4; ++j) {
                short8 b = *(const short8*)&Bs[(wc * 64 + j * 16 + m) * 32 + q * 8];
                acc[i][j] = __builtin_amdgcn_mfma_f32_16x16x32_bf16(a, b, acc[i][j], 0, 0, 0);
            }
        }
        __syncthreads();
    }
    #pragma unroll
    for (int i = 0; i < 4; ++i) {
        int rl = wr * 64 + i * 16 + q * 4;
        #pragma unroll
        for (int j = 0; j < 4; ++j) {
            int col = wc * 64 + j * 16 + m;
            float bias = b1[col];
            #pragma unroll
            for (int r = 0; r < 4; ++r)
                h1s[(rl + r) * H1P + col] = f2bf(fmaxf(acc[i][j][r] + bias, 0.f));
        }
    }
    #pragma unroll
    for (int i = 0; i < 4; ++i)
        #pragma unroll
        for (int j = 0; j < 4; ++j) acc[i][j] = zero;
    __syncthreads();

    for (int kb = 0; kb < 4; ++kb) {
        int kbase = kb * 32;
        #pragma unroll
        for (int t = 0; t < 2; ++t) {
            int nn = t * 64 + srow;
            GLDS16(W2t + (size_t)nn * 128 + kbase + scol, Bs + t * 2048 + wave * 512);
        }
        __syncthreads();
        #pragma unroll
        for (int i = 0; i < 4; ++i) {
            short8 a = *(const short8*)&h1s[(wr * 64 + i * 16 + m) * H1P + kbase + q * 8];
            #pragma unroll
            for (int j = 0; j < 4; ++j) {
                short8 b = *(const short8*)&Bs[(wc * 64 + j * 16 + m) * 32 + q * 8];
                acc[i][j] = __builtin_amdgcn_mfma_f32_16x16x32_bf16(a, b, acc[i][j], 0, 0, 0);
            }
        }
        __syncthreads();
    }
    #pragma unroll
    for (int i = 0; i < 4; ++i) {
        int grow = row0 + wr * 64 + i * 16 + q * 4;
        #pragma unroll
        for (int j = 0; j < 4; ++j) {
            int col = wc * 64 + j * 16 + m;
            #pragma unroll
            for (int r = 0; r < 4; ++r) {
                int gr = grow + r;
                if (gr < n) qp[(size_t)gr * 128 + col] = f2bf(acc[i][j][r]);
            }
        }
    }
}

// ---------------- layer-2 gather-aggregate + epilogue ----------------
__global__ void k_agg2(const u16* __restrict__ qp, const int* __restrict__ rs,
                       const int* __restrict__ csr, const float* __restrict__ b2,
                       float* __restrict__ out, int n) {
    int wid = (blockIdx.x * blockDim.x + threadIdx.x) >> 6;
    int lane = threadIdx.x & 63;
    if (wid >= n) return;
    int chunk = lane & 7;
    int oct = lane >> 3;
    int start = rs[wid];
    int deg = rs[wid + 1] - start;
    float inv = 1.0f / (1.0f + (float)deg);
    const int* nb = csr + start;
    f32x2 a0 = {0.f, 0.f}, a1 = {0.f, 0.f}, a2 = {0.f, 0.f}, a3 = {0.f, 0.f};
    int k = oct;
    for (; k + 8 < deg; k += 16) {
        int s0 = nb[k], s1 = nb[k + 8];
        uint4 u0 = *(const uint4*)(qp + (size_t)s0 * 128 + 64 + chunk * 8);
        uint4 u1 = *(const uint4*)(qp + (size_t)s1 * 128 + 64 + chunk * 8);
        a0 += bf2f2(u0.x); a1 += bf2f2(u0.y); a2 += bf2f2(u0.z); a3 += bf2f2(u0.w);
        a0 += bf2f2(u1.x); a1 += bf2f2(u1.y); a2 += bf2f2(u1.z); a3 += bf2f2(u1.w);
    }
    if (k < deg) {
        int s = nb[k];
        uint4 u = *(const uint4*)(qp + (size_t)s * 128 + 64 + chunk * 8);
        a0 += bf2f2(u.x); a1 += bf2f2(u.y); a2 += bf2f2(u.z); a3 += bf2f2(u.w);
    }
    #pragma unroll
    for (int sh = 8; sh <= 32; sh <<= 1) {
        a0.x += __shfl_xor(a0.x, sh); a0.y += __shfl_xor(a0.y, sh);
        a1.x += __shfl_xor(a1.x, sh); a1.y += __shfl_xor(a1.y, sh);
        a2.x += __shfl_xor(a2.x, sh); a2.y += __shfl_xor(a2.y, sh);
        a3.x += __shfl_xor(a3.x, sh); a3.y += __shfl_xor(a3.y, sh);
    }
    if (oct == 0) {
        uint4 up = *(const uint4*)(qp + (size_t)wid * 128 + 64 + chunk * 8);
        uint4 uq = *(const uint4*)(qp + (size_t)wid * 128 + chunk * 8);
        f32x2 p0 = bf2f2(up.x), p1 = bf2f2(up.y), p2 = bf2f2(up.z), p3 = bf2f2(up.w);
        f32x2 q0 = bf2f2(uq.x), q1 = bf2f2(uq.y), q2 = bf2f2(uq.z), q3 = bf2f2(uq.w);
        float o[8];
        o[0] = (a0.x + p0.x) * inv + q0.x;
        o[1] = (a0.y + p0.y) * inv + q0.y;
        o[2] = (a1.x + p1.x) * inv + q1.x;
        o[3] = (a1.y + p1.y) * inv + q1.y;
        o[4] = (a2.x + p2.x) * inv + q2.x;
        o[5] = (a2.y + p2.y) * inv + q2.y;
        o[6] = (a3.x + p3.x) * inv + q3.x;
        o[7] = (a3.y + p3.y) * inv + q3.y;
        float* op = out + (size_t)wid * 64 + chunk * 8;
        const float* bp = b2 + chunk * 8;
        *(float4*)(op + 0) = make_float4(o[0] + bp[0], o[1] + bp[1], o[2] + bp[2], o[3] + bp[3]);
        *(float4*)(op + 4) = make_float4(o[4] + bp[4], o[5] + bp[5], o[6] + bp[6], o[7] + bp[7]);
    }
}

extern "C" void kernel_launch(void* const* d_in, const int* in_sizes, int n_in,
                              void* d_out, int out_size, void* d_ws, size_t ws_size,
                              hipStream_t stream) {
    const float* x   = (const float*)d_in[0];
    const int*   src = (const int*)d_in[1];
    const int*   dst = (const int*)d_in[2];
    const float* Ws1 = (const float*)d_in[3];
    const float* Wn1 = (const float*)d_in[4];
    const float* b1  = (const float*)d_in[5];
    const float* Ws2 = (const float*)d_in[6];
    const float* Wn2 = (const float*)d_in[7];
    const float* b2  = (const float*)d_in[8];
    int n = in_sizes[0] / D_IN;
    int e = in_sizes[1];
    int NB = (n + 127) >> BSH;
    int T = NB * NW;
    int chunk = (e + NW - 1) / NW;
    int nblk = (T + 1023) / 1024;     // <= 128

    char* ws = (char*)d_ws;
    size_t off = 0;
    int* table = (int*)(ws + off); off = align_up(off + (size_t)T * 4, 256);
    int* bsum  = (int*)(ws + off); off = align_up(off + 128 * 4, 256);
    unsigned int* pairs = (unsigned int*)(ws + off); off = align_up(off + (size_t)e * 4, 256);
    int* rs    = (int*)(ws + off); off = align_up(off + (size_t)(n + 1) * 4, 256);
    int* csr   = (int*)(ws + off); off = align_up(off + (size_t)e * 4, 256);
    u16* xb    = (u16*)(ws + off); off = align_up(off + (size_t)n * 128 * 2, 256);
    unsigned int* xf8 = (unsigned int*)(ws + off); off = align_up(off + (size_t)n * 128, 256);
    u16* hnb   = (u16*)(ws + off); off = align_up(off + (size_t)n * 128 * 2, 256);
    u16* qp    = (u16*)(ws + off); off = align_up(off + (size_t)n * 128 * 2, 256);
    u16* W1t   = (u16*)(ws + off); off = align_up(off + (size_t)128 * 256 * 2, 256);
    u16* W2t   = (u16*)(ws + off); off = align_up(off + (size_t)128 * 128 * 2, 256);
    float* outp = (float*)d_out;

    const int B = 256;
    k_prep<<<(n * 32 + B - 1) / B, B, 0, stream>>>(x, xb, xf8, n * 32,
                                                   Ws1, Wn1, Ws2, Wn2, W1t, W2t,
                                                   dst, table, e, NB, chunk);
    k_scan1<<<nblk, 256, 0, stream>>>(table, bsum, T);
    k_wplace<<<NW, B, 0, stream>>>(src, dst, table, bsum, pairs, e, NB, chunk, nblk);
    k_bucket<<<NB, 256, 0, stream>>>(pairs, table, bsum, rs, csr, n, e, NB, nblk);
    k_agg1<<<(n + 3) / 4, B, 0, stream>>>((const u8*)xf8, xb, rs, csr, hnb, n);
    k_gemm12<<<(n + 127) / 128, 256, 0, stream>>>(xb, hnb, W1t, W2t, b1, qp, n);
    k_agg2<<<(n + 3) / 4, B, 0, stream>>>(qp, rs, csr, b2, outp, n);
}